// Round 2
// baseline (299.851 us; speedup 1.0000x reference)
//
#include <hip/hip_runtime.h>
#include <math.h>

#define NNODE 65536
#define NEDGE 1048576
#define NGRAPH 128
#define NPG 512
#define EPG 8192

typedef _Float16 f16x8 __attribute__((ext_vector_type(8)));
typedef _Float16 f16x4 __attribute__((ext_vector_type(4)));
typedef float f32x4 __attribute__((ext_vector_type(4)));

// ---- CSR build (block per graph) + init: alive, gate, dinv(layer1) ----

__global__ __launch_bounds__(512) void k_csr(const int* __restrict__ srcE, const int* __restrict__ dstE,
                                             int* __restrict__ rp, int* __restrict__ csr,
                                             float* __restrict__ gate, int* __restrict__ alive,
                                             float* __restrict__ dinv) {
    __shared__ int cnt[512];
    __shared__ int tmp[512];
    int g = blockIdx.x, t = threadIdx.x;
    int nd = g * NPG + t;
    cnt[t] = 0;
    gate[nd] = 1.f;
    alive[nd] = nd;
    __syncthreads();
    int ebase = g * EPG;
    int dl[16];
    for (int i = 0; i < 16; ++i) {
        int e = ebase + t + i * 512;
        int d = dstE[e] - g * NPG;
        dl[i] = d;
        atomicAdd(&cnt[d], 1);
    }
    __syncthreads();
    int v = cnt[t], incl = v;
    dinv[nd] = rsqrtf(1.f + (float)v);
    for (int off = 1; off < 512; off <<= 1) {
        tmp[t] = incl; __syncthreads();
        if (t >= off) incl += tmp[t - off];
        __syncthreads();
    }
    int excl = incl - v;
    rp[nd] = ebase + excl;
    if (g == NGRAPH - 1 && t == 511) rp[NNODE] = NEDGE;
    __syncthreads();
    cnt[t] = excl;
    __syncthreads();
    for (int i = 0; i < 16; ++i) {
        int e = ebase + t + i * 512;
        int pos = atomicAdd(&cnt[dl[i]], 1);
        csr[ebase + pos] = srcE[e];
    }
}

// ---- one-time: W (3 layers) -> fragment-ordered fp16 hi/lo ----

__global__ __launch_bounds__(256) void k_wconv(const float* __restrict__ W0, const float* __restrict__ W1,
                                               const float* __restrict__ W2, _Float16* __restrict__ wh,
                                               _Float16* __restrict__ wl) {
    int l = blockIdx.x >> 6;
    int e = (blockIdx.x & 63) * 256 + threadIdx.x;
    const float* W = (l == 0) ? W0 : (l == 1) ? W1 : W2;
    int k = e >> 7, n = e & 127;
    float w = W[e];
    _Float16 hi = (_Float16)w;
    _Float16 lo = (_Float16)((w - (float)hi) * 2048.0f);
    int nt = n >> 4, nn = n & 15, ks = k >> 5, quad = (k & 31) >> 3, j = k & 7;
    int off = l * 16384 + ((nt * 4 + ks) * 64 + (quad * 16 + nn)) * 8 + j;
    wh[off] = hi;
    wl[off] = lo;
}

// ---- split-fp16 MFMA GEMM v2 (unchanged from R6) ----

#define CVT8(hi8, lo8, a0, a1, a2, a3, a4, a5, a6, a7)                         \
    {                                                                           \
        _Float16 q0 = (_Float16)a0, q1 = (_Float16)a1, q2 = (_Float16)a2,       \
                 q3 = (_Float16)a3, q4 = (_Float16)a4, q5 = (_Float16)a5,       \
                 q6 = (_Float16)a6, q7 = (_Float16)a7;                          \
        hi8 = (f16x8){q0, q1, q2, q3, q4, q5, q6, q7};                          \
        lo8 = (f16x8){(_Float16)((a0 - (float)q0) * 2048.f),                    \
                      (_Float16)((a1 - (float)q1) * 2048.f),                    \
                      (_Float16)((a2 - (float)q2) * 2048.f),                    \
                      (_Float16)((a3 - (float)q3) * 2048.f),                    \
                      (_Float16)((a4 - (float)q4) * 2048.f),                    \
                      (_Float16)((a5 - (float)q5) * 2048.f),                    \
                      (_Float16)((a6 - (float)q6) * 2048.f),                    \
                      (_Float16)((a7 - (float)q7) * 2048.f)};                   \
    }

__global__ __launch_bounds__(256, 2) void k_gemm(const float* __restrict__ x0, const _Float16* __restrict__ xh,
                                                 const _Float16* __restrict__ xl, const _Float16* __restrict__ wh,
                                                 const _Float16* __restrict__ wl, const float* __restrict__ gate,
                                                 const int* __restrict__ alive, float* __restrict__ h,
                                                 int srcF32) {
    __shared__ _Float16 aH[128 * 72];
    __shared__ _Float16 aL[128 * 72];
    __shared__ _Float16 bH[8192];
    __shared__ _Float16 bL[8192];
    int t = threadIdx.x;
    int lane = t & 63;
    int wv = t >> 6;
    int quad = lane >> 4, mm = lane & 15;
    int rowbase = blockIdx.x * 128;

    f32x4 accH[2][8], accM[2][8];
    for (int a = 0; a < 2; ++a)
        for (int b = 0; b < 8; ++b) {
            accH[a][b] = (f32x4){0.f, 0.f, 0.f, 0.f};
            accM[a][b] = (f32x4){0.f, 0.f, 0.f, 0.f};
        }

    for (int kh = 0; kh < 2; ++kh) {
        if (kh) __syncthreads();
        for (int pp = 0; pp < 4; ++pp) {
            int seg = t + pp * 256;
            int nt = seg >> 7, ksl = (seg >> 6) & 1, ln = seg & 63;
            int goff = ((nt * 4 + kh * 2 + ksl) * 64 + ln) * 8;
            *(uint4*)(bH + seg * 8) = *(const uint4*)(wh + goff);
            *(uint4*)(bL + seg * 8) = *(const uint4*)(wl + goff);
        }
        for (int pp = 0; pp < 4; ++pp) {
            int c = t + pp * 256;
            int r = c >> 3, ch = c & 7;
            int node = alive[rowbase + r];
            size_t src = (size_t)node * 128 + kh * 64 + ch * 8;
            f16x8 hi8, lo8;
            if (srcF32) {
                float4 v0 = *(const float4*)(x0 + src);
                float4 v1 = *(const float4*)(x0 + src + 4);
                CVT8(hi8, lo8, v0.x, v0.y, v0.z, v0.w, v1.x, v1.y, v1.z, v1.w);
            } else {
                hi8 = *(const f16x8*)(xh + src);
                lo8 = *(const f16x8*)(xl + src);
            }
            *(f16x8*)(aH + r * 72 + ch * 8) = hi8;
            *(f16x8*)(aL + r * 72 + ch * 8) = lo8;
        }
        __syncthreads();

        for (int ksl = 0; ksl < 2; ++ksl) {
            f16x8 Ah[2], Al[2];
            for (int mt = 0; mt < 2; ++mt) {
                int row = wv * 32 + mt * 16 + mm;
                Ah[mt] = *(const f16x8*)(aH + row * 72 + ksl * 32 + quad * 8);
                Al[mt] = *(const f16x8*)(aL + row * 72 + ksl * 32 + quad * 8);
            }
            for (int nt = 0; nt < 8; ++nt) {
                f16x8 Bh = *(const f16x8*)(bH + ((nt * 2 + ksl) * 64 + lane) * 8);
                f16x8 Bl = *(const f16x8*)(bL + ((nt * 2 + ksl) * 64 + lane) * 8);
                for (int mt = 0; mt < 2; ++mt) {
                    accH[mt][nt] = __builtin_amdgcn_mfma_f32_16x16x32_f16(Ah[mt], Bh, accH[mt][nt], 0, 0, 0);
                    accM[mt][nt] = __builtin_amdgcn_mfma_f32_16x16x32_f16(Ah[mt], Bl, accM[mt][nt], 0, 0, 0);
                    accM[mt][nt] = __builtin_amdgcn_mfma_f32_16x16x32_f16(Al[mt], Bh, accM[mt][nt], 0, 0, 0);
                }
            }
        }
    }

    for (int mt = 0; mt < 2; ++mt)
        for (int i = 0; i < 4; ++i) {
            int rl = wv * 32 + mt * 16 + quad * 4 + i;
            int node = alive[rowbase + rl];
            float g = gate[node];
            float* hr = h + (size_t)node * 128 + mm;
            for (int nt = 0; nt < 8; ++nt)
                hr[nt * 16] = g * (accH[mt][nt][i] + accM[mt][nt][i] * (1.f / 2048.f));
        }
}

// ---- agg v5: FULL wave per dst; 64-slot ballot compaction split even/odd across
// lane halves (balanced: trip counts differ by <=1, no divergence waste); 8-deep
// unrolled gather (8 loads in flight per 32-lane group vs 4 before, ~1.5 rounds
// per dst vs ~5); per-group list padded to x4 with (w=0, self) so the tail stays
// vectorized; halves merged via __shfl_xor(.,32). Covers deg<=64 without the
// old serial deg>32 fallback.
// NOTE: macro param must NOT be named `w` (member access .w would be substituted).

#define FMA4(wt, hv, acc)                      \
    {                                          \
        acc.x = fmaf(wt, hv.x, acc.x);         \
        acc.y = fmaf(wt, hv.y, acc.y);         \
        acc.z = fmaf(wt, hv.z, acc.z);         \
        acc.w = fmaf(wt, hv.w, acc.w);         \
    }

__global__ __launch_bounds__(256) void k_agg(const float* __restrict__ h, const float* __restrict__ dinv,
                                             const int* __restrict__ rp, const int* __restrict__ csr,
                                             const int* __restrict__ alive, const float* __restrict__ bias,
                                             const float* __restrict__ p, _Float16* __restrict__ xh,
                                             _Float16* __restrict__ xl, float* __restrict__ score, int Kp) {
    __shared__ float2 nb[4][2][32];
    int t = threadIdx.x;
    int wv = t >> 6;
    int lane = t & 63;
    int lane32 = t & 31;
    int half = (t >> 5) & 1;
    int g = blockIdx.x & 127;          // graph = bid mod 128 (mult of 8 -> stable XCD affinity)
    int chunk = blockIdx.x >> 7;
    int idx = chunk * 4 + wv;

    int d = alive[g * Kp + idx];
    int jb = rp[d];
    int je = rp[d + 1];
    int deg = je - jb;

    // pad all 2x32 slots with (w=0, self): pad gathers hit the L1-hot self row
    nb[wv][half][lane32] = make_float2(0.f, __int_as_float(d));

    int sid = 0;
    float wvv = 0.f;
    bool livej = false;
    if (lane < deg) {                  // covers deg<=64 in one shot
        sid = csr[jb + lane];
        wvv = dinv[sid];
        livej = (wvv != 0.f);
    }
    unsigned long long bal = __ballot(livej);
    int cnt = __popcll(bal);
    if (livej) {
        int pos = __popcll(bal & ((1ull << lane) - 1ull));
        nb[wv][pos & 1][pos >> 1] = make_float2(wvv, __int_as_float(sid));
    }
    // single wave produces and consumes: wave-synchronous, no barrier

    int cg = half ? (cnt >> 1) : ((cnt + 1) >> 1);   // even positions -> group0
    int c4 = (cg + 3) & ~3;

    float dvd = dinv[d];
    float4 hd = *(const float4*)(h + (size_t)d * 128 + lane32 * 4);
    float sw = half ? 0.f : dvd;                     // self term counted once (group0)
    float4 a0, a1, a2, a3;
    a0.x = sw * hd.x; a0.y = sw * hd.y; a0.z = sw * hd.z; a0.w = sw * hd.w;
    a1 = make_float4(0.f, 0.f, 0.f, 0.f);
    a2 = a1; a3 = a1;

    const float2* nbp = &nb[wv][half][0];
    int j = 0;
    for (; j + 8 <= c4; j += 8) {
        float2 n0 = nbp[j + 0], n1 = nbp[j + 1], n2 = nbp[j + 2], n3 = nbp[j + 3];
        float2 n4 = nbp[j + 4], n5 = nbp[j + 5], n6 = nbp[j + 6], n7 = nbp[j + 7];
        float4 h0 = *(const float4*)(h + (size_t)__float_as_int(n0.y) * 128 + lane32 * 4);
        float4 h1 = *(const float4*)(h + (size_t)__float_as_int(n1.y) * 128 + lane32 * 4);
        float4 h2 = *(const float4*)(h + (size_t)__float_as_int(n2.y) * 128 + lane32 * 4);
        float4 h3 = *(const float4*)(h + (size_t)__float_as_int(n3.y) * 128 + lane32 * 4);
        float4 h4 = *(const float4*)(h + (size_t)__float_as_int(n4.y) * 128 + lane32 * 4);
        float4 h5 = *(const float4*)(h + (size_t)__float_as_int(n5.y) * 128 + lane32 * 4);
        float4 h6 = *(const float4*)(h + (size_t)__float_as_int(n6.y) * 128 + lane32 * 4);
        float4 h7 = *(const float4*)(h + (size_t)__float_as_int(n7.y) * 128 + lane32 * 4);
        FMA4(n0.x, h0, a0); FMA4(n1.x, h1, a1); FMA4(n2.x, h2, a2); FMA4(n3.x, h3, a3);
        FMA4(n4.x, h4, a0); FMA4(n5.x, h5, a1); FMA4(n6.x, h6, a2); FMA4(n7.x, h7, a3);
    }
    if (j < c4) {                                    // exactly one padded 4-round
        float2 n0 = nbp[j + 0], n1 = nbp[j + 1], n2 = nbp[j + 2], n3 = nbp[j + 3];
        float4 h0 = *(const float4*)(h + (size_t)__float_as_int(n0.y) * 128 + lane32 * 4);
        float4 h1 = *(const float4*)(h + (size_t)__float_as_int(n1.y) * 128 + lane32 * 4);
        float4 h2 = *(const float4*)(h + (size_t)__float_as_int(n2.y) * 128 + lane32 * 4);
        float4 h3 = *(const float4*)(h + (size_t)__float_as_int(n3.y) * 128 + lane32 * 4);
        FMA4(n0.x, h0, a0); FMA4(n1.x, h1, a1); FMA4(n2.x, h2, a2); FMA4(n3.x, h3, a3);
    }
    if (half == 0) {                                 // deg>64: essentially never (Poisson(16))
        for (int j2 = jb + 64; j2 < je; ++j2) {
            int s2 = csr[j2];
            float w2 = dinv[s2];
            float4 h2 = *(const float4*)(h + (size_t)s2 * 128 + lane32 * 4);
            FMA4(w2, h2, a0);
        }
    }

    float4 s;
    s.x = a0.x + a1.x + a2.x + a3.x;
    s.y = a0.y + a1.y + a2.y + a3.y;
    s.z = a0.z + a1.z + a2.z + a3.z;
    s.w = a0.w + a1.w + a2.w + a3.w;
    s.x += __shfl_xor(s.x, 32);
    s.y += __shfl_xor(s.y, 32);
    s.z += __shfl_xor(s.z, 32);
    s.w += __shfl_xor(s.w, 32);

    float4 b4 = *(const float4*)(bias + lane32 * 4);
    float4 o;
    o.x = fmaxf(fmaf(dvd, s.x, b4.x), 0.f);
    o.y = fmaxf(fmaf(dvd, s.y, b4.y), 0.f);
    o.z = fmaxf(fmaf(dvd, s.z, b4.z), 0.f);
    o.w = fmaxf(fmaf(dvd, s.w, b4.w), 0.f);

    if (half == 0) {
        _Float16 q0 = (_Float16)o.x, q1 = (_Float16)o.y, q2 = (_Float16)o.z, q3 = (_Float16)o.w;
        f16x4 oh = {q0, q1, q2, q3};
        f16x4 ol = {(_Float16)((o.x - (float)q0) * 2048.f), (_Float16)((o.y - (float)q1) * 2048.f),
                    (_Float16)((o.z - (float)q2) * 2048.f), (_Float16)((o.w - (float)q3) * 2048.f)};
        *(f16x4*)(xh + (size_t)d * 128 + lane32 * 4) = oh;
        *(f16x4*)(xl + (size_t)d * 128 + lane32 * 4) = ol;
    }

    float4 p4 = *(const float4*)(p + lane32 * 4);
    float ps = o.x * p4.x + o.y * p4.y + o.z * p4.z + o.w * p4.w;
    float q = p4.x * p4.x + p4.y * p4.y + p4.z * p4.z + p4.w * p4.w;
    for (int m = 16; m >= 1; m >>= 1) {
        ps += __shfl_xor(ps, m);
        q += __shfl_xor(q, m);
    }
    if (lane == 0) score[d] = 1.f / (1.f + expf(-ps * rsqrtf(q)));
}

// ---- pool v2: radix-select top-k (histogram of score bits) + readout + next dinv ----

__global__ __launch_bounds__(512) void k_pool(const _Float16* __restrict__ xh, const _Float16* __restrict__ xl,
                                              const float* __restrict__ score, float* __restrict__ gate,
                                              int* __restrict__ alive, float* __restrict__ hg,
                                              const int* __restrict__ rp, const int* __restrict__ csr,
                                              float* __restrict__ dinv, int K, int last) {
    __shared__ unsigned hist[1024];
    __shared__ unsigned wsum[8];
    __shared__ float cand[512];
    __shared__ int ad[256];
    __shared__ float ag[256];
    __shared__ float red[1024];
    __shared__ int m_new[512];
    __shared__ int scnt;
    __shared__ unsigned ccnt;
    __shared__ unsigned tbb, tbab;
    __shared__ float thrS;
    int t = threadIdx.x, g = blockIdx.x;
    int gbase = g * NPG;
    int d = gbase + t;

    float odv = dinv[d];
    int m = odv > 0.f;
    float sc = score[d];
    // positive floats are order-isomorphic to their bit patterns; dead -> bucket 0
    unsigned bits = m ? __float_as_uint(sc) : 0u;
    unsigned bucket = bits >> 21;    // <= 508 for sc <= 1.0
    hist[t] = 0; hist[t + 512] = 0;
    if (t == 0) { scnt = 0; ccnt = 0; }
    __syncthreads();
    atomicAdd(&hist[bucket], 1u);
    __syncthreads();
    // suffix-sum (descending buckets): thread t owns reversed pair (1023-2t, 1022-2t)
    unsigned a0 = hist[1023 - 2 * t];
    unsigned a1 = hist[1022 - 2 * t];
    unsigned pair = a0 + a1;
    unsigned v = pair;
    for (int o = 1; o < 64; o <<= 1) {
        unsigned n = __shfl_up(v, o);
        if ((t & 63) >= o) v += n;
    }
    if ((t & 63) == 63) wsum[t >> 6] = v;
    __syncthreads();
    if (t == 0) {
        unsigned run = 0;
        for (int i = 0; i < 8; ++i) { unsigned x = wsum[i]; wsum[i] = run; run += x; }
    }
    __syncthreads();
    unsigned incl = v + wsum[t >> 6];
    unsigned excl = incl - pair;
    unsigned uK = (unsigned)K;
    if (excl < uK && excl + a0 >= uK) { tbb = 1023 - 2 * t; tbab = excl; }
    else if (excl + a0 < uK && incl >= uK) { tbb = 1022 - 2 * t; tbab = excl + a0; }
    __syncthreads();
    unsigned bsel = tbb;
    unsigned r = uK - tbab;                      // 1-indexed rank inside bucket
    if (m && bucket == bsel) {
        unsigned pos = atomicAdd(&ccnt, 1u);
        cand[pos] = sc;
    }
    __syncthreads();
    unsigned c = ccnt;
    if (t < (int)c) {
        float vv = cand[t];
        unsigned gt = 0;
        for (unsigned i = 0; i < c; ++i) gt += (cand[i] > vv) ? 1u : 0u;
        if (gt == r - 1) thrS = vv;
    }
    __syncthreads();
    float thr = thrS;

    int nm = (m && sc >= thr) ? 1 : 0;
    gate[d] = nm ? sc : 0.f;
    m_new[t] = nm;
    if (nm) {
        int pos = atomicAdd(&scnt, 1);
        if (pos < K) {
            alive[g * K + pos] = d;
            ad[pos] = d;
            ag[pos] = sc;
        }
    }
    __syncthreads();

    if (!last) {
        float nd = 0.f;
        if (nm) {
            int jb = rp[d], je = rp[d + 1];
            int sum = 0;
            for (int j = jb; j < je; ++j) sum += m_new[csr[j] - gbase];
            nd = rsqrtf(1.f + (float)sum);
        }
        dinv[d] = nd;
    }

    int f = t & 127, c2 = t >> 7;
    float mx = 0.f, sm = 0.f;
#define REC(node) ((float)xh[(size_t)(node)*128 + f] + (float)xl[(size_t)(node)*128 + f] * (1.f / 2048.f))
    for (int j = c2; j < K; j += 16) {
        float v0 = REC(ad[j]) * ag[j];
        float v1 = REC(ad[j + 4]) * ag[j + 4];
        float v2 = REC(ad[j + 8]) * ag[j + 8];
        float v3 = REC(ad[j + 12]) * ag[j + 12];
        mx = fmaxf(fmaxf(fmaxf(mx, v0), fmaxf(v1, v2)), v3);
        sm += v0 + v1 + v2 + v3;
    }
#undef REC
    red[t] = mx; red[512 + t] = sm;
    __syncthreads();
    if (c2 == 0) {
        for (int cc = 1; cc < 4; ++cc) {
            mx = fmaxf(mx, red[cc * 128 + f]);
            sm += red[512 + cc * 128 + f];
        }
        hg[g * 256 + f] += mx;
        hg[g * 256 + 128 + f] += sm / (float)K;
    }
}

// ---------------- fused MLP head ----------------

__global__ __launch_bounds__(256) void k_mlp(const float* __restrict__ inp_c, const float* __restrict__ hg,
                                             const float* __restrict__ We, const float* __restrict__ Wa,
                                             const float* __restrict__ ba, const float* __restrict__ Wb,
                                             const float* __restrict__ bb, const float* __restrict__ Wc,
                                             float* __restrict__ out) {
    __shared__ float fus[320];
    __shared__ float h1[256];
    __shared__ float h2[128];
    int t = threadIdx.x, g = blockIdx.x;
    if (t < 64) {
        float a = 0.f;
        for (int j = 0; j < 64; ++j) a = fmaf(inp_c[g * 64 + j], We[j * 64 + t], a);
        fus[t] = fmaxf(a, 0.f);
    }
    fus[64 + t] = hg[g * 256 + t];
    __syncthreads();
    {
        float a = ba[t];
        for (int j = 0; j < 320; ++j) a = fmaf(fus[j], Wa[j * 256 + t], a);
        h1[t] = fmaxf(a, 0.f);
    }
    __syncthreads();
    if (t < 128) {
        float a = bb[t];
        for (int j = 0; j < 256; ++j) a = fmaf(h1[j], Wb[j * 128 + t], a);
        h2[t] = fmaxf(a, 0.f);
    }
    __syncthreads();
    if (t == 0) {
        float a = 0.f;
        for (int j = 0; j < 128; ++j) a = fmaf(h2[j], Wc[j], a);
        out[g] = a;
    }
}

// ---------------- launch ----------------

extern "C" void kernel_launch(void* const* d_in, const int* in_sizes, int n_in,
                              void* d_out, int out_size, void* d_ws, size_t ws_size,
                              hipStream_t stream) {
    (void)in_sizes; (void)n_in; (void)out_size; (void)ws_size;
    const float* x_in  = (const float*)d_in[0];
    const float* inp_c = (const float*)d_in[1];
    const int*   ei    = (const int*)d_in[2];
    const int* srcE = ei;
    const int* dstE = ei + NEDGE;
    const float* Wl[3] = {(const float*)d_in[4], (const float*)d_in[6], (const float*)d_in[8]};
    const float* bl[3] = {(const float*)d_in[5], (const float*)d_in[7], (const float*)d_in[9]};
    const float* Pl[3] = {(const float*)d_in[10], (const float*)d_in[11], (const float*)d_in[12]};
    const float* We = (const float*)d_in[13];
    const float* Wa = (const float*)d_in[14];
    const float* ba = (const float*)d_in[15];
    const float* Wb = (const float*)d_in[16];
    const float* bb = (const float*)d_in[17];
    const float* Wc = (const float*)d_in[18];
    float* out = (float*)d_out;

    char* w = (char*)d_ws;
    size_t off = 0;
    auto alloc = [&](size_t bytes) -> void* {
        void* p = w + off;
        off = (off + bytes + 255) & ~(size_t)255;
        return p;
    };
    int*   rp    = (int*)alloc((NNODE + 1) * 4);
    int*   csr   = (int*)alloc(NEDGE * 4);
    float* dinv  = (float*)alloc(NNODE * 4);
    float* gate  = (float*)alloc(NNODE * 4);
    float* score = (float*)alloc(NNODE * 4);
    int*   alive = (int*)alloc(NNODE * 4);
    float* hbuf  = (float*)alloc((size_t)NNODE * 128 * 4);
    _Float16* xh = (_Float16*)alloc((size_t)NNODE * 128 * 2);
    _Float16* xl = (_Float16*)alloc((size_t)NNODE * 128 * 2);
    float* hg    = (float*)alloc(NGRAPH * 256 * 4);
    _Float16* wfh = (_Float16*)alloc(3 * 16384 * 2);
    _Float16* wfl = (_Float16*)alloc(3 * 16384 * 2);

    hipMemsetAsync(hg, 0, NGRAPH * 256 * 4, stream);
    k_wconv<<<192, 256, 0, stream>>>(Wl[0], Wl[1], Wl[2], wfh, wfl);
    k_csr<<<NGRAPH, 512, 0, stream>>>(srcE, dstE, rp, csr, gate, alive, dinv);

    const int rows_in[3] = {65536, 32768, 16384};
    const int Ks[3] = {256, 128, 64};
    const int Kp[3] = {512, 256, 128};
    for (int l = 0; l < 3; ++l) {
        k_gemm<<<rows_in[l] / 128, 256, 0, stream>>>(x_in, xh, xl, wfh + l * 16384, wfl + l * 16384,
                                                     gate, alive, hbuf, l == 0);
        k_agg<<<rows_in[l] / 4, 256, 0, stream>>>(hbuf, dinv, rp, csr, alive, bl[l], Pl[l],
                                                  xh, xl, score, Kp[l]);
        k_pool<<<NGRAPH, 512, 0, stream>>>(xh, xl, score, gate, alive, hg,
                                           rp, csr, dinv, Ks[l], l == 2);
    }
    k_mlp<<<NGRAPH, 256, 0, stream>>>(inp_c, hg, We, Wa, ba, Wb, bb, Wc, out);
}

// Round 3
// 286.131 us; speedup vs baseline: 1.0479x; 1.0479x over previous
//
#include <hip/hip_runtime.h>
#include <math.h>

#define NNODE 65536
#define NEDGE 1048576
#define NGRAPH 128
#define NPG 512
#define EPG 8192

typedef _Float16 f16x8 __attribute__((ext_vector_type(8)));
typedef _Float16 f16x4 __attribute__((ext_vector_type(4)));
typedef float f32x4 __attribute__((ext_vector_type(4)));

// ---- CSR build (block per graph) + init: alive, gate, dinv(layer1) ----

__global__ __launch_bounds__(512) void k_csr(const int* __restrict__ srcE, const int* __restrict__ dstE,
                                             int* __restrict__ rp, int* __restrict__ csr,
                                             float* __restrict__ gate, int* __restrict__ alive,
                                             float* __restrict__ dinv) {
    __shared__ int cnt[512];
    __shared__ int tmp[512];
    int g = blockIdx.x, t = threadIdx.x;
    int nd = g * NPG + t;
    cnt[t] = 0;
    gate[nd] = 1.f;
    alive[nd] = nd;
    __syncthreads();
    int ebase = g * EPG;
    int dl[16];
    for (int i = 0; i < 16; ++i) {
        int e = ebase + t + i * 512;
        int d = dstE[e] - g * NPG;
        dl[i] = d;
        atomicAdd(&cnt[d], 1);
    }
    __syncthreads();
    int v = cnt[t], incl = v;
    dinv[nd] = rsqrtf(1.f + (float)v);
    for (int off = 1; off < 512; off <<= 1) {
        tmp[t] = incl; __syncthreads();
        if (t >= off) incl += tmp[t - off];
        __syncthreads();
    }
    int excl = incl - v;
    rp[nd] = ebase + excl;
    if (g == NGRAPH - 1 && t == 511) rp[NNODE] = NEDGE;
    __syncthreads();
    cnt[t] = excl;
    __syncthreads();
    for (int i = 0; i < 16; ++i) {
        int e = ebase + t + i * 512;
        int pos = atomicAdd(&cnt[dl[i]], 1);
        csr[ebase + pos] = srcE[e];
    }
}

// ---- one-time: W (3 layers) -> fragment-ordered fp16 hi/lo ----

__global__ __launch_bounds__(256) void k_wconv(const float* __restrict__ W0, const float* __restrict__ W1,
                                               const float* __restrict__ W2, _Float16* __restrict__ wh,
                                               _Float16* __restrict__ wl) {
    int l = blockIdx.x >> 6;
    int e = (blockIdx.x & 63) * 256 + threadIdx.x;
    const float* W = (l == 0) ? W0 : (l == 1) ? W1 : W2;
    int k = e >> 7, n = e & 127;
    float w = W[e];
    _Float16 hi = (_Float16)w;
    _Float16 lo = (_Float16)((w - (float)hi) * 2048.0f);
    int nt = n >> 4, nn = n & 15, ks = k >> 5, quad = (k & 31) >> 3, j = k & 7;
    int off = l * 16384 + ((nt * 4 + ks) * 64 + (quad * 16 + nn)) * 8 + j;
    wh[off] = hi;
    wl[off] = lo;
}

// ---- split-fp16 MFMA GEMM v3: graph-affine block mapping ----
// bid = c*128 + g  ->  rows [g*perg + c*128, +128).  XCD(bid) = bid%8 = g%8, which
// matches k_agg (g = bid&127), k_pool (bid = g), k_csr (bid = g).  The per-graph
// h / xh / xl windows (256KB + 128KB) then stay in ONE XCD's L2 across
// gemm -> agg -> pool -> next gemm, converting IF$-latency gathers to L2 hits.

#define CVT8(hi8, lo8, a0, a1, a2, a3, a4, a5, a6, a7)                         \
    {                                                                           \
        _Float16 q0 = (_Float16)a0, q1 = (_Float16)a1, q2 = (_Float16)a2,       \
                 q3 = (_Float16)a3, q4 = (_Float16)a4, q5 = (_Float16)a5,       \
                 q6 = (_Float16)a6, q7 = (_Float16)a7;                          \
        hi8 = (f16x8){q0, q1, q2, q3, q4, q5, q6, q7};                          \
        lo8 = (f16x8){(_Float16)((a0 - (float)q0) * 2048.f),                    \
                      (_Float16)((a1 - (float)q1) * 2048.f),                    \
                      (_Float16)((a2 - (float)q2) * 2048.f),                    \
                      (_Float16)((a3 - (float)q3) * 2048.f),                    \
                      (_Float16)((a4 - (float)q4) * 2048.f),                    \
                      (_Float16)((a5 - (float)q5) * 2048.f),                    \
                      (_Float16)((a6 - (float)q6) * 2048.f),                    \
                      (_Float16)((a7 - (float)q7) * 2048.f)};                   \
    }

__global__ __launch_bounds__(256, 2) void k_gemm(const float* __restrict__ x0, const _Float16* __restrict__ xh,
                                                 const _Float16* __restrict__ xl, const _Float16* __restrict__ wh,
                                                 const _Float16* __restrict__ wl, const float* __restrict__ gate,
                                                 const int* __restrict__ alive, float* __restrict__ h,
                                                 int srcF32, int perg) {
    __shared__ _Float16 aH[128 * 72];
    __shared__ _Float16 aL[128 * 72];
    __shared__ _Float16 bH[8192];
    __shared__ _Float16 bL[8192];
    int t = threadIdx.x;
    int lane = t & 63;
    int wv = t >> 6;
    int quad = lane >> 4, mm = lane & 15;
    int gg = blockIdx.x & 127;
    int cc0 = blockIdx.x >> 7;
    int rowbase = gg * perg + cc0 * 128;

    f32x4 accH[2][8], accM[2][8];
    for (int a = 0; a < 2; ++a)
        for (int b = 0; b < 8; ++b) {
            accH[a][b] = (f32x4){0.f, 0.f, 0.f, 0.f};
            accM[a][b] = (f32x4){0.f, 0.f, 0.f, 0.f};
        }

    for (int kh = 0; kh < 2; ++kh) {
        if (kh) __syncthreads();
        for (int pp = 0; pp < 4; ++pp) {
            int seg = t + pp * 256;
            int nt = seg >> 7, ksl = (seg >> 6) & 1, ln = seg & 63;
            int goff = ((nt * 4 + kh * 2 + ksl) * 64 + ln) * 8;
            *(uint4*)(bH + seg * 8) = *(const uint4*)(wh + goff);
            *(uint4*)(bL + seg * 8) = *(const uint4*)(wl + goff);
        }
        for (int pp = 0; pp < 4; ++pp) {
            int c = t + pp * 256;
            int r = c >> 3, ch = c & 7;
            int node = alive[rowbase + r];
            size_t src = (size_t)node * 128 + kh * 64 + ch * 8;
            f16x8 hi8, lo8;
            if (srcF32) {
                float4 v0 = *(const float4*)(x0 + src);
                float4 v1 = *(const float4*)(x0 + src + 4);
                CVT8(hi8, lo8, v0.x, v0.y, v0.z, v0.w, v1.x, v1.y, v1.z, v1.w);
            } else {
                hi8 = *(const f16x8*)(xh + src);
                lo8 = *(const f16x8*)(xl + src);
            }
            *(f16x8*)(aH + r * 72 + ch * 8) = hi8;
            *(f16x8*)(aL + r * 72 + ch * 8) = lo8;
        }
        __syncthreads();

        for (int ksl = 0; ksl < 2; ++ksl) {
            f16x8 Ah[2], Al[2];
            for (int mt = 0; mt < 2; ++mt) {
                int row = wv * 32 + mt * 16 + mm;
                Ah[mt] = *(const f16x8*)(aH + row * 72 + ksl * 32 + quad * 8);
                Al[mt] = *(const f16x8*)(aL + row * 72 + ksl * 32 + quad * 8);
            }
            for (int nt = 0; nt < 8; ++nt) {
                f16x8 Bh = *(const f16x8*)(bH + ((nt * 2 + ksl) * 64 + lane) * 8);
                f16x8 Bl = *(const f16x8*)(bL + ((nt * 2 + ksl) * 64 + lane) * 8);
                for (int mt = 0; mt < 2; ++mt) {
                    accH[mt][nt] = __builtin_amdgcn_mfma_f32_16x16x32_f16(Ah[mt], Bh, accH[mt][nt], 0, 0, 0);
                    accM[mt][nt] = __builtin_amdgcn_mfma_f32_16x16x32_f16(Ah[mt], Bl, accM[mt][nt], 0, 0, 0);
                    accM[mt][nt] = __builtin_amdgcn_mfma_f32_16x16x32_f16(Al[mt], Bh, accM[mt][nt], 0, 0, 0);
                }
            }
        }
    }

    for (int mt = 0; mt < 2; ++mt)
        for (int i = 0; i < 4; ++i) {
            int rl = wv * 32 + mt * 16 + quad * 4 + i;
            int node = alive[rowbase + rl];
            float g = gate[node];
            float* hr = h + (size_t)node * 128 + mm;
            for (int nt = 0; nt < 8; ++nt)
                hr[nt * 16] = g * (accH[mt][nt][i] + accM[mt][nt][i] * (1.f / 2048.f));
        }
}

// ---- agg v4 (REVERTED to R0 / proven 46.6us form): half-wave per dst;
// 32-neighbor prefetch+compaction; 4x-unrolled gather ----

__global__ __launch_bounds__(256) void k_agg(const float* __restrict__ h, const float* __restrict__ dinv,
                                             const int* __restrict__ rp, const int* __restrict__ csr,
                                             const int* __restrict__ alive, const float* __restrict__ bias,
                                             const float* __restrict__ p, _Float16* __restrict__ xh,
                                             _Float16* __restrict__ xl, float* __restrict__ score, int Kp) {
    __shared__ float2 nb[8][32];
    int t = threadIdx.x;
    int slot = t >> 5;
    int lane32 = t & 31;
    int half = slot & 1;
    int g = blockIdx.x & 127;
    int chunk = blockIdx.x >> 7;
    int idx = chunk * 8 + slot;

    int d = alive[g * Kp + idx];
    int jb = rp[d];
    int je = rp[d + 1];
    int deg = je - jb;

    int sid = 0; float wv = 0.f; bool livej = false;
    if (lane32 < deg) {
        sid = csr[jb + lane32];
        wv = dinv[sid];
        livej = (wv != 0.f);
    }
    unsigned long long bal = __ballot(livej);
    unsigned hm = (unsigned)(bal >> (half * 32));
    int cnt = __popc(hm);
    if (livej) {
        int pos = __popc(hm & ((1u << lane32) - 1));
        nb[slot][pos] = make_float2(wv, __int_as_float(sid));
    }
    // producer half-wave == consumer half-wave: wave-synchronous, no barrier

    float dvd = dinv[d];
    float4 hd = *(const float4*)(h + (size_t)d * 128 + lane32 * 4);
    float4 a0, a1, a2, a3;
    a0.x = dvd * hd.x; a0.y = dvd * hd.y; a0.z = dvd * hd.z; a0.w = dvd * hd.w;
    a1 = make_float4(0.f, 0.f, 0.f, 0.f);
    a2 = a1; a3 = a1;

    int j = 0;
    for (; j + 4 <= cnt; j += 4) {
        float2 n0 = nb[slot][j];
        float2 n1 = nb[slot][j + 1];
        float2 n2 = nb[slot][j + 2];
        float2 n3 = nb[slot][j + 3];
        float4 h0 = *(const float4*)(h + (size_t)__float_as_int(n0.y) * 128 + lane32 * 4);
        float4 h1 = *(const float4*)(h + (size_t)__float_as_int(n1.y) * 128 + lane32 * 4);
        float4 h2 = *(const float4*)(h + (size_t)__float_as_int(n2.y) * 128 + lane32 * 4);
        float4 h3 = *(const float4*)(h + (size_t)__float_as_int(n3.y) * 128 + lane32 * 4);
        a0.x = fmaf(n0.x, h0.x, a0.x); a0.y = fmaf(n0.x, h0.y, a0.y);
        a0.z = fmaf(n0.x, h0.z, a0.z); a0.w = fmaf(n0.x, h0.w, a0.w);
        a1.x = fmaf(n1.x, h1.x, a1.x); a1.y = fmaf(n1.x, h1.y, a1.y);
        a1.z = fmaf(n1.x, h1.z, a1.z); a1.w = fmaf(n1.x, h1.w, a1.w);
        a2.x = fmaf(n2.x, h2.x, a2.x); a2.y = fmaf(n2.x, h2.y, a2.y);
        a2.z = fmaf(n2.x, h2.z, a2.z); a2.w = fmaf(n2.x, h2.w, a2.w);
        a3.x = fmaf(n3.x, h3.x, a3.x); a3.y = fmaf(n3.x, h3.y, a3.y);
        a3.z = fmaf(n3.x, h3.z, a3.z); a3.w = fmaf(n3.x, h3.w, a3.w);
    }
    for (; j < cnt; ++j) {
        float2 n0 = nb[slot][j];
        float4 h0 = *(const float4*)(h + (size_t)__float_as_int(n0.y) * 128 + lane32 * 4);
        a0.x = fmaf(n0.x, h0.x, a0.x); a0.y = fmaf(n0.x, h0.y, a0.y);
        a0.z = fmaf(n0.x, h0.z, a0.z); a0.w = fmaf(n0.x, h0.w, a0.w);
    }
    for (int j2 = jb + 32; j2 < je; ++j2) {   // deg>32: ~1e-4 of dsts
        int s2 = csr[j2];
        float w2 = dinv[s2];
        float4 h2 = *(const float4*)(h + (size_t)s2 * 128 + lane32 * 4);
        a0.x = fmaf(w2, h2.x, a0.x); a0.y = fmaf(w2, h2.y, a0.y);
        a0.z = fmaf(w2, h2.z, a0.z); a0.w = fmaf(w2, h2.w, a0.w);
    }

    float4 b4 = *(const float4*)(bias + lane32 * 4);
    float4 o;
    o.x = fmaxf(fmaf(dvd, a0.x + a1.x + a2.x + a3.x, b4.x), 0.f);
    o.y = fmaxf(fmaf(dvd, a0.y + a1.y + a2.y + a3.y, b4.y), 0.f);
    o.z = fmaxf(fmaf(dvd, a0.z + a1.z + a2.z + a3.z, b4.z), 0.f);
    o.w = fmaxf(fmaf(dvd, a0.w + a1.w + a2.w + a3.w, b4.w), 0.f);

    _Float16 q0 = (_Float16)o.x, q1 = (_Float16)o.y, q2 = (_Float16)o.z, q3 = (_Float16)o.w;
    f16x4 oh = {q0, q1, q2, q3};
    f16x4 ol = {(_Float16)((o.x - (float)q0) * 2048.f), (_Float16)((o.y - (float)q1) * 2048.f),
                (_Float16)((o.z - (float)q2) * 2048.f), (_Float16)((o.w - (float)q3) * 2048.f)};
    *(f16x4*)(xh + (size_t)d * 128 + lane32 * 4) = oh;
    *(f16x4*)(xl + (size_t)d * 128 + lane32 * 4) = ol;

    float4 p4 = *(const float4*)(p + lane32 * 4);
    float ps = o.x * p4.x + o.y * p4.y + o.z * p4.z + o.w * p4.w;
    float q = p4.x * p4.x + p4.y * p4.y + p4.z * p4.z + p4.w * p4.w;
    for (int m = 16; m >= 1; m >>= 1) {
        ps += __shfl_xor(ps, m);
        q += __shfl_xor(q, m);
    }
    if (lane32 == 0) score[d] = 1.f / (1.f + expf(-ps * rsqrtf(q)));
}

// ---- pool v2: radix-select top-k (histogram of score bits) + readout + next dinv ----

__global__ __launch_bounds__(512) void k_pool(const _Float16* __restrict__ xh, const _Float16* __restrict__ xl,
                                              const float* __restrict__ score, float* __restrict__ gate,
                                              int* __restrict__ alive, float* __restrict__ hg,
                                              const int* __restrict__ rp, const int* __restrict__ csr,
                                              float* __restrict__ dinv, int K, int last) {
    __shared__ unsigned hist[1024];
    __shared__ unsigned wsum[8];
    __shared__ float cand[512];
    __shared__ int ad[256];
    __shared__ float ag[256];
    __shared__ float red[1024];
    __shared__ int m_new[512];
    __shared__ int scnt;
    __shared__ unsigned ccnt;
    __shared__ unsigned tbb, tbab;
    __shared__ float thrS;
    int t = threadIdx.x, g = blockIdx.x;
    int gbase = g * NPG;
    int d = gbase + t;

    float odv = dinv[d];
    int m = odv > 0.f;
    float sc = score[d];
    // positive floats are order-isomorphic to their bit patterns; dead -> bucket 0
    unsigned bits = m ? __float_as_uint(sc) : 0u;
    unsigned bucket = bits >> 21;    // <= 508 for sc <= 1.0
    hist[t] = 0; hist[t + 512] = 0;
    if (t == 0) { scnt = 0; ccnt = 0; }
    __syncthreads();
    atomicAdd(&hist[bucket], 1u);
    __syncthreads();
    // suffix-sum (descending buckets): thread t owns reversed pair (1023-2t, 1022-2t)
    unsigned a0 = hist[1023 - 2 * t];
    unsigned a1 = hist[1022 - 2 * t];
    unsigned pair = a0 + a1;
    unsigned v = pair;
    for (int o = 1; o < 64; o <<= 1) {
        unsigned n = __shfl_up(v, o);
        if ((t & 63) >= o) v += n;
    }
    if ((t & 63) == 63) wsum[t >> 6] = v;
    __syncthreads();
    if (t == 0) {
        unsigned run = 0;
        for (int i = 0; i < 8; ++i) { unsigned x = wsum[i]; wsum[i] = run; run += x; }
    }
    __syncthreads();
    unsigned incl = v + wsum[t >> 6];
    unsigned excl = incl - pair;
    unsigned uK = (unsigned)K;
    if (excl < uK && excl + a0 >= uK) { tbb = 1023 - 2 * t; tbab = excl; }
    else if (excl + a0 < uK && incl >= uK) { tbb = 1022 - 2 * t; tbab = excl + a0; }
    __syncthreads();
    unsigned bsel = tbb;
    unsigned r = uK - tbab;                      // 1-indexed rank inside bucket
    if (m && bucket == bsel) {
        unsigned pos = atomicAdd(&ccnt, 1u);
        cand[pos] = sc;
    }
    __syncthreads();
    unsigned c = ccnt;
    if (t < (int)c) {
        float vv = cand[t];
        unsigned gt = 0;
        for (unsigned i = 0; i < c; ++i) gt += (cand[i] > vv) ? 1u : 0u;
        if (gt == r - 1) thrS = vv;
    }
    __syncthreads();
    float thr = thrS;

    int nm = (m && sc >= thr) ? 1 : 0;
    gate[d] = nm ? sc : 0.f;
    m_new[t] = nm;
    if (nm) {
        int pos = atomicAdd(&scnt, 1);
        if (pos < K) {
            alive[g * K + pos] = d;
            ad[pos] = d;
            ag[pos] = sc;
        }
    }
    __syncthreads();

    if (!last) {
        float nd = 0.f;
        if (nm) {
            int jb = rp[d], je = rp[d + 1];
            int sum = 0;
            for (int j = jb; j < je; ++j) sum += m_new[csr[j] - gbase];
            nd = rsqrtf(1.f + (float)sum);
        }
        dinv[d] = nd;
    }

    int f = t & 127, c2 = t >> 7;
    float mx = 0.f, sm = 0.f;
#define REC(node) ((float)xh[(size_t)(node)*128 + f] + (float)xl[(size_t)(node)*128 + f] * (1.f / 2048.f))
    for (int j = c2; j < K; j += 16) {
        float v0 = REC(ad[j]) * ag[j];
        float v1 = REC(ad[j + 4]) * ag[j + 4];
        float v2 = REC(ad[j + 8]) * ag[j + 8];
        float v3 = REC(ad[j + 12]) * ag[j + 12];
        mx = fmaxf(fmaxf(fmaxf(mx, v0), fmaxf(v1, v2)), v3);
        sm += v0 + v1 + v2 + v3;
    }
#undef REC
    red[t] = mx; red[512 + t] = sm;
    __syncthreads();
    if (c2 == 0) {
        for (int cc = 1; cc < 4; ++cc) {
            mx = fmaxf(mx, red[cc * 128 + f]);
            sm += red[512 + cc * 128 + f];
        }
        hg[g * 256 + f] += mx;
        hg[g * 256 + 128 + f] += sm / (float)K;
    }
}

// ---------------- fused MLP head ----------------

__global__ __launch_bounds__(256) void k_mlp(const float* __restrict__ inp_c, const float* __restrict__ hg,
                                             const float* __restrict__ We, const float* __restrict__ Wa,
                                             const float* __restrict__ ba, const float* __restrict__ Wb,
                                             const float* __restrict__ bb, const float* __restrict__ Wc,
                                             float* __restrict__ out) {
    __shared__ float fus[320];
    __shared__ float h1[256];
    __shared__ float h2[128];
    int t = threadIdx.x, g = blockIdx.x;
    if (t < 64) {
        float a = 0.f;
        for (int j = 0; j < 64; ++j) a = fmaf(inp_c[g * 64 + j], We[j * 64 + t], a);
        fus[t] = fmaxf(a, 0.f);
    }
    fus[64 + t] = hg[g * 256 + t];
    __syncthreads();
    {
        float a = ba[t];
        for (int j = 0; j < 320; ++j) a = fmaf(fus[j], Wa[j * 256 + t], a);
        h1[t] = fmaxf(a, 0.f);
    }
    __syncthreads();
    if (t < 128) {
        float a = bb[t];
        for (int j = 0; j < 256; ++j) a = fmaf(h1[j], Wb[j * 128 + t], a);
        h2[t] = fmaxf(a, 0.f);
    }
    __syncthreads();
    if (t == 0) {
        float a = 0.f;
        for (int j = 0; j < 128; ++j) a = fmaf(h2[j], Wc[j], a);
        out[g] = a;
    }
}

// ---------------- launch ----------------

extern "C" void kernel_launch(void* const* d_in, const int* in_sizes, int n_in,
                              void* d_out, int out_size, void* d_ws, size_t ws_size,
                              hipStream_t stream) {
    (void)in_sizes; (void)n_in; (void)out_size; (void)ws_size;
    const float* x_in  = (const float*)d_in[0];
    const float* inp_c = (const float*)d_in[1];
    const int*   ei    = (const int*)d_in[2];
    const int* srcE = ei;
    const int* dstE = ei + NEDGE;
    const float* Wl[3] = {(const float*)d_in[4], (const float*)d_in[6], (const float*)d_in[8]};
    const float* bl[3] = {(const float*)d_in[5], (const float*)d_in[7], (const float*)d_in[9]};
    const float* Pl[3] = {(const float*)d_in[10], (const float*)d_in[11], (const float*)d_in[12]};
    const float* We = (const float*)d_in[13];
    const float* Wa = (const float*)d_in[14];
    const float* ba = (const float*)d_in[15];
    const float* Wb = (const float*)d_in[16];
    const float* bb = (const float*)d_in[17];
    const float* Wc = (const float*)d_in[18];
    float* out = (float*)d_out;

    char* w = (char*)d_ws;
    size_t off = 0;
    auto alloc = [&](size_t bytes) -> void* {
        void* p = w + off;
        off = (off + bytes + 255) & ~(size_t)255;
        return p;
    };
    int*   rp    = (int*)alloc((NNODE + 1) * 4);
    int*   csr   = (int*)alloc(NEDGE * 4);
    float* dinv  = (float*)alloc(NNODE * 4);
    float* gate  = (float*)alloc(NNODE * 4);
    float* score = (float*)alloc(NNODE * 4);
    int*   alive = (int*)alloc(NNODE * 4);
    float* hbuf  = (float*)alloc((size_t)NNODE * 128 * 4);
    _Float16* xh = (_Float16*)alloc((size_t)NNODE * 128 * 2);
    _Float16* xl = (_Float16*)alloc((size_t)NNODE * 128 * 2);
    float* hg    = (float*)alloc(NGRAPH * 256 * 4);
    _Float16* wfh = (_Float16*)alloc(3 * 16384 * 2);
    _Float16* wfl = (_Float16*)alloc(3 * 16384 * 2);

    hipMemsetAsync(hg, 0, NGRAPH * 256 * 4, stream);
    k_wconv<<<192, 256, 0, stream>>>(Wl[0], Wl[1], Wl[2], wfh, wfl);
    k_csr<<<NGRAPH, 512, 0, stream>>>(srcE, dstE, rp, csr, gate, alive, dinv);

    const int rows_in[3] = {65536, 32768, 16384};
    const int Ks[3] = {256, 128, 64};
    const int Kp[3] = {512, 256, 128};
    for (int l = 0; l < 3; ++l) {
        k_gemm<<<rows_in[l] / 128, 256, 0, stream>>>(x_in, xh, xl, wfh + l * 16384, wfl + l * 16384,
                                                     gate, alive, hbuf, l == 0, rows_in[l] / 128);
        k_agg<<<rows_in[l] / 8, 256, 0, stream>>>(hbuf, dinv, rp, csr, alive, bl[l], Pl[l],
                                                  xh, xl, score, Kp[l]);
        k_pool<<<NGRAPH, 512, 0, stream>>>(xh, xl, score, gate, alive, hg,
                                           rp, csr, dinv, Ks[l], l == 2);
    }
    k_mlp<<<NGRAPH, 256, 0, stream>>>(inp_c, hg, We, Wa, ba, Wb, bb, Wc, out);
}